// Round 11
// baseline (169.735 us; speedup 1.0000x reference)
//
#include <hip/hip_runtime.h>

#define NN 50000
#define NE 1600000
#define DD 128

// ---- L1 bucketing: 391 buckets of 128 dst nodes ----
#define L1T 512
#define VPT 4
#define EPB (L1T * VPT)                  // 2048 edges/block
#define NB1 ((NE + EPB - 1) / EPB)       // 782
#define NBUCK ((NN + 127) >> 7)          // 391
#define BSTRIDE 5120                     // mean 4096, sigma~64 -> +16 sigma
#define GBLK ((NN + 31) / 32)            // 1563 gemm tiles
#define GGRID 512                        // persistent gemm blocks (2/CU)
#define AGRID 2048                       // agg blocks (grid-stride over nodes)

typedef __attribute__((ext_vector_type(8))) short bf16x8;
typedef __attribute__((ext_vector_type(4))) float f32x4;
typedef __attribute__((ext_vector_type(2))) float f32x2;

__device__ __forceinline__ ushort f2b(float f) {
    unsigned u = __float_as_uint(f);
    return (ushort)((u + 0x7FFFu + ((u >> 16) & 1u)) >> 16);   // RNE
}

// ---------------- L1: bucket edges by dst>>7 + fused prep (xq cvt, Wsw build) ----------------

__global__ __launch_bounds__(L1T) void l1_scatter(const int* __restrict__ src,
                                                  const int* __restrict__ dst,
                                                  int* __restrict__ g_fill,
                                                  unsigned* __restrict__ l1out,
                                                  const float* __restrict__ x,
                                                  unsigned* __restrict__ xq,
                                                  const float* __restrict__ W1l,
                                                  const float* __restrict__ W1r,
                                                  const float* __restrict__ W2l,
                                                  const float* __restrict__ W2r,
                                                  ushort* __restrict__ Wsw1,
                                                  ushort* __restrict__ Wsw2) {
    __shared__ int lhist[L1T];
    __shared__ int lscan[L1T];
    __shared__ int lrsv[L1T];
    __shared__ int lfill[L1T];
    __shared__ int wsum[8];
    __shared__ unsigned staged[EPB];
    int tid = threadIdx.x;
    int gt = blockIdx.x * L1T + tid;

    // --- fused prep: x -> fp8 (4 u32/thread) ---
#pragma unroll
    for (int i = 0; i < 4; ++i) {
        int idx = gt + i * (NB1 * L1T);
        if (idx < NN * DD / 4) {
            float4 v = ((const float4*)x)[idx];
            int w = __builtin_amdgcn_cvt_pk_fp8_f32(v.x, v.y, 0, false);
            w = __builtin_amdgcn_cvt_pk_fp8_f32(v.z, v.w, w, true);
            xq[idx] = (unsigned)w;
        }
    }
    // --- fused prep: swizzled bf16 weights (first 128 blocks) ---
    if (gt < 65536) {
        int which = gt >> 15, r = gt & 32767;
        int c = r >> 8, k = r & 255;
        const float* Wl = which ? W2l : W1l;
        const float* Wr = which ? W2r : W1r;
        ushort* Wsw = which ? Wsw2 : Wsw1;
        float v = (k < 128) ? Wl[c * 128 + k] : Wr[c * 128 + (k - 128)];
        Wsw[((k >> 5) * 128 + c) * 32 + (k & 31)] = f2b(v);
    }

    lhist[tid] = 0;
    lfill[tid] = 0;
    __syncthreads();

    unsigned myv[VPT];
    int base = blockIdx.x * EPB;
#pragma unroll
    for (int i = 0; i < VPT; ++i) {
        int idx = base + i * L1T + tid;
        if (idx < NE) {
            unsigned d = (unsigned)dst[idx], s = (unsigned)src[idx];
            myv[i] = (d << 16) | s;
            atomicAdd(&lhist[d >> 7], 1);
        } else {
            myv[i] = 0xFFFFFFFFu;
        }
    }
    __syncthreads();

    // inclusive shfl scan of lhist -> lscan
    int lane = tid & 63, wv = tid >> 6;
    {
        int sv = lhist[tid];
#pragma unroll
        for (int off = 1; off < 64; off <<= 1) {
            int t = __shfl_up(sv, off, 64);
            if (lane >= off) sv += t;
        }
        if (lane == 63) wsum[wv] = sv;
        __syncthreads();
        if (tid < 8) {
            int w = wsum[tid], sw = w;
#pragma unroll
            for (int off = 1; off < 8; off <<= 1) {
                int t = __shfl_up(sw, off, 64);
                if (tid >= off) sw += t;
            }
            wsum[tid] = sw - w;                 // exclusive wave offset
        }
        __syncthreads();
        lscan[tid] = sv + wsum[wv];
    }
    __syncthreads();

    int cntb = lhist[tid];
    if (cntb > 0) lrsv[tid] = atomicAdd(&g_fill[tid], cntb);

#pragma unroll
    for (int i = 0; i < VPT; ++i) {
        unsigned v = myv[i];
        if (v != 0xFFFFFFFFu) {
            int b = (v >> 16) >> 7;
            int p = lscan[b] - lhist[b] + atomicAdd(&lfill[b], 1);
            staged[p] = v;
        }
    }
    __syncthreads();

    int n = lscan[L1T - 1];
    for (int i = tid; i < n; i += L1T) {
        unsigned v = staged[i];
        int b = (v >> 16) >> 7;
        int g = lrsv[b] + (i - (lscan[b] - lhist[b]));
        if (g < BSTRIDE) l1out[(size_t)b * BSTRIDE + g] = v;
    }
}

// ---------------- L2: per bucket, group by (node, src>>13), emit rp + u16 src ----------------

__global__ __launch_bounds__(1024) void l2_kernel(const int* __restrict__ g_fill,
                                                  const unsigned* __restrict__ l1out,
                                                  unsigned short* __restrict__ su,
                                                  int* __restrict__ rp) {
    int B = blockIdx.x;
    int tid = threadIdx.x;
    int lane = tid & 63, wv = tid >> 6;
    __shared__ int gsc[512];
    __shared__ int ws1[8];
    __shared__ int ws2[16];
    __shared__ int h2[1024], sc[1024], f2[1024];

    // exclusive scan of g_fill (512 wide) -> bucket base
    int gsv = 0;
    if (tid < 512) {
        gsv = (tid < NBUCK) ? g_fill[tid] : 0;
#pragma unroll
        for (int off = 1; off < 64; off <<= 1) {
            int t = __shfl_up(gsv, off, 64);
            if (lane >= off) gsv += t;
        }
        if (lane == 63) ws1[wv] = gsv;
    }
    h2[tid] = 0;
    f2[tid] = 0;
    __syncthreads();
    if (tid < 8) {
        int w = ws1[tid], sw = w;
#pragma unroll
        for (int off = 1; off < 8; off <<= 1) {
            int t = __shfl_up(sw, off, 64);
            if (tid >= off) sw += t;
        }
        ws1[tid] = sw - w;
    }
    __syncthreads();
    if (tid < 512) gsc[tid] = gsv + ws1[wv];
    __syncthreads();

    int base = gsc[B] - g_fill[B];
    int cnt = g_fill[B];
    if (cnt > BSTRIDE) cnt = BSTRIDE;

    const unsigned* in = l1out + (size_t)B * BSTRIDE;
    for (int i = tid; i < cnt; i += 1024) {
        unsigned v = in[i];
        int key = (int)((v >> 16) & 127) * 8 + (int)((v & 0xFFFFu) >> 13);
        atomicAdd(&h2[key], 1);
    }
    __syncthreads();

    // inclusive shfl scan of h2 (1024 wide) -> sc
    {
        int sv = h2[tid];
#pragma unroll
        for (int off = 1; off < 64; off <<= 1) {
            int t = __shfl_up(sv, off, 64);
            if (lane >= off) sv += t;
        }
        if (lane == 63) ws2[wv] = sv;
        __syncthreads();
        if (tid < 16) {
            int w = ws2[tid], sw = w;
#pragma unroll
            for (int off = 1; off < 16; off <<= 1) {
                int t = __shfl_up(sw, off, 64);
                if (tid >= off) sw += t;
            }
            ws2[tid] = sw - w;
        }
        __syncthreads();
        sc[tid] = sv + ws2[wv];
    }
    __syncthreads();

    if ((tid & 7) == 0) {
        int n = B * 128 + (tid >> 3);
        if (n < NN) rp[n] = base + sc[tid] - h2[tid];
    }
    if (B == 0 && tid == 0) rp[NN] = NE;
    __syncthreads();
    for (int i = tid; i < cnt; i += 1024) {
        unsigned v = in[i];
        int key = (int)((v >> 16) & 127) * 8 + (int)((v & 0xFFFFu) >> 13);
        int p = atomicAdd(&f2[key], 1);
        su[base + sc[key] - h2[key] + p] = (unsigned short)(v & 0xFFFFu);
    }
}

// ---------------- aggregation: one wave per node, fp8 rows, 8 slots x uint4 (16B/lane) ----------------
// Half the gather instructions of the uint2 version (discriminating experiment:
// VMEM-issue-bound vs cache-line-service-bound).

#define ADD16(V) { f32x2 t_;                                                         \
    t_ = __builtin_amdgcn_cvt_pk_f32_fp8(V.x, false); acc[0]  += t_.x; acc[1]  += t_.y; \
    t_ = __builtin_amdgcn_cvt_pk_f32_fp8(V.x, true);  acc[2]  += t_.x; acc[3]  += t_.y; \
    t_ = __builtin_amdgcn_cvt_pk_f32_fp8(V.y, false); acc[4]  += t_.x; acc[5]  += t_.y; \
    t_ = __builtin_amdgcn_cvt_pk_f32_fp8(V.y, true);  acc[6]  += t_.x; acc[7]  += t_.y; \
    t_ = __builtin_amdgcn_cvt_pk_f32_fp8(V.z, false); acc[8]  += t_.x; acc[9]  += t_.y; \
    t_ = __builtin_amdgcn_cvt_pk_f32_fp8(V.z, true);  acc[10] += t_.x; acc[11] += t_.y; \
    t_ = __builtin_amdgcn_cvt_pk_f32_fp8(V.w, false); acc[12] += t_.x; acc[13] += t_.y; \
    t_ = __builtin_amdgcn_cvt_pk_f32_fp8(V.w, true);  acc[14] += t_.x; acc[15] += t_.y; }

__global__ __launch_bounds__(256) void agg_fp8(const unsigned char* __restrict__ xq,
                                               const int* __restrict__ rp,
                                               const unsigned short* __restrict__ su,
                                               ushort* __restrict__ meanb) {
    int wave = threadIdx.x >> 6, lane = threadIdx.x & 63;
    int eslot = lane >> 3, chunk = lane & 7;     // 8 slots x 8 lanes; 16B per lane
    for (int node = blockIdx.x * 4 + wave; node < NN; node += AGRID * 4) {
        int start = __builtin_amdgcn_readfirstlane(rp[node]);
        int end   = __builtin_amdgcn_readfirstlane(rp[node + 1]);
        float acc[16] = {};
        int e = start + eslot;
        for (; e + 24 < end; e += 32) {            // 4 gathers in flight per lane, 32 edges/iter
            unsigned s0 = su[e], s1 = su[e + 8], s2 = su[e + 16], s3 = su[e + 24];
            uint4 v0 = *(const uint4*)(xq + (size_t)s0 * 128 + chunk * 16);
            uint4 v1 = *(const uint4*)(xq + (size_t)s1 * 128 + chunk * 16);
            uint4 v2 = *(const uint4*)(xq + (size_t)s2 * 128 + chunk * 16);
            uint4 v3 = *(const uint4*)(xq + (size_t)s3 * 128 + chunk * 16);
            ADD16(v0); ADD16(v1); ADD16(v2); ADD16(v3);
        }
        for (; e < end; e += 8) {                  // tail, 1 in flight
            unsigned s0 = su[e];
            uint4 v0 = *(const uint4*)(xq + (size_t)s0 * 128 + chunk * 16);
            ADD16(v0);
        }
#pragma unroll
        for (int j = 0; j < 16; ++j) {
            acc[j] += __shfl_xor(acc[j], 8, 64);
            acc[j] += __shfl_xor(acc[j], 16, 64);
            acc[j] += __shfl_xor(acc[j], 32, 64);
        }
        if (eslot == 0) {
            int cnt = end - start;
            float inv = 1.0f / (float)(cnt > 1 ? cnt : 1);
            unsigned p[8];
#pragma unroll
            for (int i = 0; i < 8; ++i)
                p[i] = (unsigned)f2b(acc[2 * i] * inv) | ((unsigned)f2b(acc[2 * i + 1] * inv) << 16);
            uint4 o0 = {p[0], p[1], p[2], p[3]};
            uint4 o1 = {p[4], p[5], p[6], p[7]};
            *(uint4*)(meanb + (size_t)node * DD + chunk * 16) = o0;
            *(uint4*)(meanb + (size_t)node * DD + chunk * 16 + 8) = o1;
        }
    }
}

// ---------------- persistent MFMA GEMM: stage Wsw once, loop over 32-row tiles ----------------

template <int L1>
__global__ __launch_bounds__(256) void gemm_mfma(const ushort* __restrict__ meanb,
                                                 const float* __restrict__ xf,
                                                 const ushort* __restrict__ ah,
                                                 const ushort* __restrict__ Wsw,
                                                 const float* __restrict__ bias,
                                                 float* __restrict__ outf,
                                                 ushort* __restrict__ outh,
                                                 unsigned char* __restrict__ outq) {
    __shared__ __align__(16) ushort WbL[8][128][32];   // 64KB
    int tid = threadIdx.x;
    int wave = tid >> 6, lane = tid & 63;
    int wave_r = wave >> 1, wave_c = wave & 1;
    int c0 = wave_c * 64;
    int kg = (lane >> 4) * 8;
    int c = lane & 15;

    {
        const uint4* Wg = (const uint4*)Wsw;
        uint4* Wl4 = (uint4*)&WbL[0][0][0];
#pragma unroll
        for (int it = 0; it < 16; ++it) Wl4[it * 256 + tid] = Wg[it * 256 + tid];
    }
    float bj[4];
#pragma unroll
    for (int t = 0; t < 4; ++t) bj[t] = bias[c0 + t * 16 + c];
    __syncthreads();

    for (int tile = blockIdx.x; tile < GBLK; tile += GGRID) {
        int r0 = tile * 32 + wave_r * 16;
        int arow = r0 + (lane & 15);
        if (arow >= NN) arow = NN - 1;           // clamp reads; writes guarded

        bf16x8 af[8];
#pragma unroll
        for (int kc = 0; kc < 4; ++kc)
            af[kc] = *(const bf16x8*)(meanb + (size_t)arow * 128 + kc * 32 + kg);
#pragma unroll
        for (int kc = 4; kc < 8; ++kc) {
            if (L1) {
                const float* ap = xf + (size_t)arow * 128 + (kc - 4) * 32 + kg;
                float4 a = *(const float4*)ap;
                float4 b = *(const float4*)(ap + 4);
                bf16x8 v;
                v[0] = (short)f2b(a.x); v[1] = (short)f2b(a.y);
                v[2] = (short)f2b(a.z); v[3] = (short)f2b(a.w);
                v[4] = (short)f2b(b.x); v[5] = (short)f2b(b.y);
                v[6] = (short)f2b(b.z); v[7] = (short)f2b(b.w);
                af[kc] = v;
            } else {
                af[kc] = *(const bf16x8*)(ah + (size_t)arow * 128 + (kc - 4) * 32 + kg);
            }
        }

        f32x4 acc[4] = {};
#pragma unroll
        for (int kc = 0; kc < 8; ++kc) {
#pragma unroll
            for (int t = 0; t < 4; ++t) {
                bf16x8 bf = *(const bf16x8*)&WbL[kc][c0 + t * 16 + c][kg];
                acc[t] = __builtin_amdgcn_mfma_f32_16x16x32_bf16(af[kc], bf, acc[t], 0, 0, 0);
            }
        }

        int rbase = r0 + (lane >> 4) * 4;
#pragma unroll
        for (int t = 0; t < 4; ++t) {
#pragma unroll
            for (int i = 0; i < 4; ++i) {
                int r = rbase + i;
                if (r < NN) {
                    float v = acc[t][i] + bj[t];
                    if (L1) {
                        v = fmaxf(v, 0.f);
                        outh[(size_t)r * 128 + c0 + t * 16 + c] = f2b(v);
                        int q = __builtin_amdgcn_cvt_pk_fp8_f32(v, v, 0, false);
                        outq[(size_t)r * 128 + c0 + t * 16 + c] = (unsigned char)q;
                    } else {
                        outf[(size_t)r * 128 + c0 + t * 16 + c] = v;
                    }
                }
            }
        }
    }
}

// ---------------- launch ----------------

extern "C" void kernel_launch(void* const* d_in, const int* in_sizes, int n_in,
                              void* d_out, int out_size, void* d_ws, size_t ws_size,
                              hipStream_t stream) {
    const float* x   = (const float*)d_in[0];
    const int*   ei  = (const int*)d_in[1];
    const float* W1l = (const float*)d_in[2];
    const float* b1  = (const float*)d_in[3];
    const float* W1r = (const float*)d_in[4];
    const float* W2l = (const float*)d_in[5];
    const float* b2  = (const float*)d_in[6];
    const float* W2r = (const float*)d_in[7];
    float* out = (float*)d_out;

    const int* src = ei;
    const int* dst = ei + NE;

    char* ws = (char*)d_ws;
    size_t off = 0;
    auto carve = [&](size_t bytes) {
        char* p = ws + off;
        off = (off + bytes + 255) & ~(size_t)255;
        return p;
    };
    int*            rp     = (int*)carve((NN + 1) * sizeof(int));
    int*            g_fill = (int*)carve(512 * sizeof(int));
    unsigned short* su     = (unsigned short*)carve((size_t)NE * sizeof(unsigned short));
    unsigned*       xq     = (unsigned*)carve((size_t)NN * DD);                 // fp8 x
    unsigned char*  hq     = (unsigned char*)carve((size_t)NN * DD);            // fp8 relu(h)
    ushort*         meanb  = (ushort*)carve((size_t)NN * DD * sizeof(ushort));  // bf16 mean
    ushort*         hh     = (ushort*)carve((size_t)NN * DD * sizeof(ushort));  // bf16 relu(h)
    ushort*         Wsw1   = (ushort*)carve(128 * 256 * sizeof(ushort));
    ushort*         Wsw2   = (ushort*)carve(128 * 256 * sizeof(ushort));
    unsigned*       l1out  = (unsigned*)hh;   // 8.0MB <= 12.8MB; dead before gemm1 writes hh

    hipMemsetAsync(g_fill, 0, 512 * sizeof(int), stream);

    l1_scatter<<<NB1, L1T, 0, stream>>>(src, dst, g_fill, l1out,
                                        x, xq, W1l, W1r, W2l, W2r, Wsw1, Wsw2);
    l2_kernel<<<NBUCK, 1024, 0, stream>>>(g_fill, l1out, su, rp);

    // layer 1
    agg_fp8<<<AGRID, 256, 0, stream>>>((const unsigned char*)xq, rp, su, meanb);
    gemm_mfma<1><<<GGRID, 256, 0, stream>>>(meanb, x, nullptr, Wsw1, b1, nullptr, hh, hq);

    // layer 2
    agg_fp8<<<AGRID, 256, 0, stream>>>(hq, rp, su, meanb);
    gemm_mfma<0><<<GGRID, 256, 0, stream>>>(meanb, nullptr, hh, Wsw2, b2, out, nullptr, nullptr);
}

// Round 12
// 140.007 us; speedup vs baseline: 1.2123x; 1.2123x over previous
//
#include <hip/hip_runtime.h>

#define NN 50000
#define NE 1600000
#define DD 128

// ---- L1 bucketing: 391 buckets of 128 dst nodes ----
#define L1T 512
#define VPT 4
#define EPB (L1T * VPT)                  // 2048 edges/block
#define NB1 ((NE + EPB - 1) / EPB)       // 782
#define NBUCK ((NN + 127) >> 7)          // 391
#define BSTRIDE 5120                     // mean 4096, sigma~64 -> +16 sigma
#define GBLK ((NN + 31) / 32)            // 1563 gemm tiles
#define GGRID 512                        // persistent gemm blocks (2/CU)
#define AGRID 2048                       // agg blocks (grid-stride over nodes)

typedef __attribute__((ext_vector_type(8))) short bf16x8;
typedef __attribute__((ext_vector_type(4))) float f32x4;
typedef __attribute__((ext_vector_type(2))) float f32x2;

__device__ __forceinline__ ushort f2b(float f) {
    unsigned u = __float_as_uint(f);
    return (ushort)((u + 0x7FFFu + ((u >> 16) & 1u)) >> 16);   // RNE
}

// ---------------- L1: bucket edges by dst>>7 + fused prep (xq cvt, Wsw build) ----------------

__global__ __launch_bounds__(L1T) void l1_scatter(const int* __restrict__ src,
                                                  const int* __restrict__ dst,
                                                  int* __restrict__ g_fill,
                                                  unsigned* __restrict__ l1out,
                                                  const float* __restrict__ x,
                                                  unsigned* __restrict__ xq,
                                                  const float* __restrict__ W1l,
                                                  const float* __restrict__ W1r,
                                                  const float* __restrict__ W2l,
                                                  const float* __restrict__ W2r,
                                                  ushort* __restrict__ Wsw1,
                                                  ushort* __restrict__ Wsw2) {
    __shared__ int lhist[L1T];
    __shared__ int lscan[L1T];
    __shared__ int lrsv[L1T];
    __shared__ int lfill[L1T];
    __shared__ int wsum[8];
    __shared__ unsigned staged[EPB];
    int tid = threadIdx.x;
    int gt = blockIdx.x * L1T + tid;

    // --- fused prep: x -> fp8 (4 u32/thread) ---
#pragma unroll
    for (int i = 0; i < 4; ++i) {
        int idx = gt + i * (NB1 * L1T);
        if (idx < NN * DD / 4) {
            float4 v = ((const float4*)x)[idx];
            int w = __builtin_amdgcn_cvt_pk_fp8_f32(v.x, v.y, 0, false);
            w = __builtin_amdgcn_cvt_pk_fp8_f32(v.z, v.w, w, true);
            xq[idx] = (unsigned)w;
        }
    }
    // --- fused prep: swizzled bf16 weights (first 128 blocks) ---
    if (gt < 65536) {
        int which = gt >> 15, r = gt & 32767;
        int c = r >> 8, k = r & 255;
        const float* Wl = which ? W2l : W1l;
        const float* Wr = which ? W2r : W1r;
        ushort* Wsw = which ? Wsw2 : Wsw1;
        float v = (k < 128) ? Wl[c * 128 + k] : Wr[c * 128 + (k - 128)];
        Wsw[((k >> 5) * 128 + c) * 32 + (k & 31)] = f2b(v);
    }

    lhist[tid] = 0;
    lfill[tid] = 0;
    __syncthreads();

    unsigned myv[VPT];
    int base = blockIdx.x * EPB;
#pragma unroll
    for (int i = 0; i < VPT; ++i) {
        int idx = base + i * L1T + tid;
        if (idx < NE) {
            unsigned d = (unsigned)dst[idx], s = (unsigned)src[idx];
            myv[i] = (d << 16) | s;
            atomicAdd(&lhist[d >> 7], 1);
        } else {
            myv[i] = 0xFFFFFFFFu;
        }
    }
    __syncthreads();

    // inclusive shfl scan of lhist -> lscan
    int lane = tid & 63, wv = tid >> 6;
    {
        int sv = lhist[tid];
#pragma unroll
        for (int off = 1; off < 64; off <<= 1) {
            int t = __shfl_up(sv, off, 64);
            if (lane >= off) sv += t;
        }
        if (lane == 63) wsum[wv] = sv;
        __syncthreads();
        if (tid < 8) {
            int w = wsum[tid], sw = w;
#pragma unroll
            for (int off = 1; off < 8; off <<= 1) {
                int t = __shfl_up(sw, off, 64);
                if (tid >= off) sw += t;
            }
            wsum[tid] = sw - w;                 // exclusive wave offset
        }
        __syncthreads();
        lscan[tid] = sv + wsum[wv];
    }
    __syncthreads();

    int cntb = lhist[tid];
    if (cntb > 0) lrsv[tid] = atomicAdd(&g_fill[tid], cntb);

#pragma unroll
    for (int i = 0; i < VPT; ++i) {
        unsigned v = myv[i];
        if (v != 0xFFFFFFFFu) {
            int b = (v >> 16) >> 7;
            int p = lscan[b] - lhist[b] + atomicAdd(&lfill[b], 1);
            staged[p] = v;
        }
    }
    __syncthreads();

    int n = lscan[L1T - 1];
    for (int i = tid; i < n; i += L1T) {
        unsigned v = staged[i];
        int b = (v >> 16) >> 7;
        int g = lrsv[b] + (i - (lscan[b] - lhist[b]));
        if (g < BSTRIDE) l1out[(size_t)b * BSTRIDE + g] = v;
    }
}

// ---------------- L2: per bucket, group by (node, src>>13), emit rp + u16 src ----------------

__global__ __launch_bounds__(1024) void l2_kernel(const int* __restrict__ g_fill,
                                                  const unsigned* __restrict__ l1out,
                                                  unsigned short* __restrict__ su,
                                                  int* __restrict__ rp) {
    int B = blockIdx.x;
    int tid = threadIdx.x;
    int lane = tid & 63, wv = tid >> 6;
    __shared__ int gsc[512];
    __shared__ int ws1[8];
    __shared__ int ws2[16];
    __shared__ int h2[1024], sc[1024], f2[1024];

    // exclusive scan of g_fill (512 wide) -> bucket base
    int gsv = 0;
    if (tid < 512) {
        gsv = (tid < NBUCK) ? g_fill[tid] : 0;
#pragma unroll
        for (int off = 1; off < 64; off <<= 1) {
            int t = __shfl_up(gsv, off, 64);
            if (lane >= off) gsv += t;
        }
        if (lane == 63) ws1[wv] = gsv;
    }
    h2[tid] = 0;
    f2[tid] = 0;
    __syncthreads();
    if (tid < 8) {
        int w = ws1[tid], sw = w;
#pragma unroll
        for (int off = 1; off < 8; off <<= 1) {
            int t = __shfl_up(sw, off, 64);
            if (tid >= off) sw += t;
        }
        ws1[tid] = sw - w;
    }
    __syncthreads();
    if (tid < 512) gsc[tid] = gsv + ws1[wv];
    __syncthreads();

    int base = gsc[B] - g_fill[B];
    int cnt = g_fill[B];
    if (cnt > BSTRIDE) cnt = BSTRIDE;

    const unsigned* in = l1out + (size_t)B * BSTRIDE;
    for (int i = tid; i < cnt; i += 1024) {
        unsigned v = in[i];
        int key = (int)((v >> 16) & 127) * 8 + (int)((v & 0xFFFFu) >> 13);
        atomicAdd(&h2[key], 1);
    }
    __syncthreads();

    // inclusive shfl scan of h2 (1024 wide) -> sc
    {
        int sv = h2[tid];
#pragma unroll
        for (int off = 1; off < 64; off <<= 1) {
            int t = __shfl_up(sv, off, 64);
            if (lane >= off) sv += t;
        }
        if (lane == 63) ws2[wv] = sv;
        __syncthreads();
        if (tid < 16) {
            int w = ws2[tid], sw = w;
#pragma unroll
            for (int off = 1; off < 16; off <<= 1) {
                int t = __shfl_up(sw, off, 64);
                if (tid >= off) sw += t;
            }
            ws2[tid] = sw - w;
        }
        __syncthreads();
        sc[tid] = sv + ws2[wv];
    }
    __syncthreads();

    if ((tid & 7) == 0) {
        int n = B * 128 + (tid >> 3);
        if (n < NN) rp[n] = base + sc[tid] - h2[tid];
    }
    if (B == 0 && tid == 0) rp[NN] = NE;
    __syncthreads();
    for (int i = tid; i < cnt; i += 1024) {
        unsigned v = in[i];
        int key = (int)((v >> 16) & 127) * 8 + (int)((v & 0xFFFFu) >> 13);
        int p = atomicAdd(&f2[key], 1);
        su[base + sc[key] - h2[key] + p] = (unsigned short)(v & 0xFFFFu);
    }
}

// ---------------- aggregation: one wave per node, fp8 rows, 4 slots x 8-deep (uint2) ----------------
// Best-known config (R10): 16 lanes/row x 8B; at the ~125G segs/s gather ceiling.

#define ADD8(V) { f32x2 t_;                                                         \
    t_ = __builtin_amdgcn_cvt_pk_f32_fp8(V.x, false); acc[0] += t_.x; acc[1] += t_.y; \
    t_ = __builtin_amdgcn_cvt_pk_f32_fp8(V.x, true);  acc[2] += t_.x; acc[3] += t_.y; \
    t_ = __builtin_amdgcn_cvt_pk_f32_fp8(V.y, false); acc[4] += t_.x; acc[5] += t_.y; \
    t_ = __builtin_amdgcn_cvt_pk_f32_fp8(V.y, true);  acc[6] += t_.x; acc[7] += t_.y; }

__global__ __launch_bounds__(256) void agg_fp8(const unsigned char* __restrict__ xq,
                                               const int* __restrict__ rp,
                                               const unsigned short* __restrict__ su,
                                               ushort* __restrict__ meanb) {
    int wave = threadIdx.x >> 6, lane = threadIdx.x & 63;
    int eslot = lane >> 4, chunk = lane & 15;
    for (int node = blockIdx.x * 4 + wave; node < NN; node += AGRID * 4) {
        int start = __builtin_amdgcn_readfirstlane(rp[node]);
        int end   = __builtin_amdgcn_readfirstlane(rp[node + 1]);
        float acc[8] = {};
        int e = start + eslot;
        for (; e + 28 < end; e += 32) {            // 8 gathers in flight per lane
            unsigned s0 = su[e],      s1 = su[e + 4],  s2 = su[e + 8],  s3 = su[e + 12];
            unsigned s4 = su[e + 16], s5 = su[e + 20], s6 = su[e + 24], s7 = su[e + 28];
            uint2 v0 = *(const uint2*)(xq + (size_t)s0 * 128 + chunk * 8);
            uint2 v1 = *(const uint2*)(xq + (size_t)s1 * 128 + chunk * 8);
            uint2 v2 = *(const uint2*)(xq + (size_t)s2 * 128 + chunk * 8);
            uint2 v3 = *(const uint2*)(xq + (size_t)s3 * 128 + chunk * 8);
            uint2 v4 = *(const uint2*)(xq + (size_t)s4 * 128 + chunk * 8);
            uint2 v5 = *(const uint2*)(xq + (size_t)s5 * 128 + chunk * 8);
            uint2 v6 = *(const uint2*)(xq + (size_t)s6 * 128 + chunk * 8);
            uint2 v7 = *(const uint2*)(xq + (size_t)s7 * 128 + chunk * 8);
            ADD8(v0); ADD8(v1); ADD8(v2); ADD8(v3);
            ADD8(v4); ADD8(v5); ADD8(v6); ADD8(v7);
        }
        for (; e + 4 < end; e += 8) {              // 2 in flight
            unsigned s0 = su[e], s1 = su[e + 4];
            uint2 v0 = *(const uint2*)(xq + (size_t)s0 * 128 + chunk * 8);
            uint2 v1 = *(const uint2*)(xq + (size_t)s1 * 128 + chunk * 8);
            ADD8(v0); ADD8(v1);
        }
        if (e < end) {
            unsigned s0 = su[e];
            uint2 v0 = *(const uint2*)(xq + (size_t)s0 * 128 + chunk * 8);
            ADD8(v0);
        }
#pragma unroll
        for (int j = 0; j < 8; ++j) {
            acc[j] += __shfl_xor(acc[j], 16, 64);
            acc[j] += __shfl_xor(acc[j], 32, 64);
        }
        if (eslot == 0) {
            int cnt = end - start;
            float inv = 1.0f / (float)(cnt > 1 ? cnt : 1);
            uint4 o;
            o.x = (unsigned)f2b(acc[0] * inv) | ((unsigned)f2b(acc[1] * inv) << 16);
            o.y = (unsigned)f2b(acc[2] * inv) | ((unsigned)f2b(acc[3] * inv) << 16);
            o.z = (unsigned)f2b(acc[4] * inv) | ((unsigned)f2b(acc[5] * inv) << 16);
            o.w = (unsigned)f2b(acc[6] * inv) | ((unsigned)f2b(acc[7] * inv) << 16);
            *(uint4*)(meanb + (size_t)node * DD + chunk * 8) = o;
        }
    }
}

// ---------------- persistent MFMA GEMM: stage Wsw once, loop over 32-row tiles ----------------

template <int L1>
__global__ __launch_bounds__(256) void gemm_mfma(const ushort* __restrict__ meanb,
                                                 const float* __restrict__ xf,
                                                 const ushort* __restrict__ ah,
                                                 const ushort* __restrict__ Wsw,
                                                 const float* __restrict__ bias,
                                                 float* __restrict__ outf,
                                                 ushort* __restrict__ outh,
                                                 unsigned char* __restrict__ outq) {
    __shared__ __align__(16) ushort WbL[8][128][32];   // 64KB
    int tid = threadIdx.x;
    int wave = tid >> 6, lane = tid & 63;
    int wave_r = wave >> 1, wave_c = wave & 1;
    int c0 = wave_c * 64;
    int kg = (lane >> 4) * 8;
    int c = lane & 15;

    {
        const uint4* Wg = (const uint4*)Wsw;
        uint4* Wl4 = (uint4*)&WbL[0][0][0];
#pragma unroll
        for (int it = 0; it < 16; ++it) Wl4[it * 256 + tid] = Wg[it * 256 + tid];
    }
    float bj[4];
#pragma unroll
    for (int t = 0; t < 4; ++t) bj[t] = bias[c0 + t * 16 + c];
    __syncthreads();

    for (int tile = blockIdx.x; tile < GBLK; tile += GGRID) {
        int r0 = tile * 32 + wave_r * 16;
        int arow = r0 + (lane & 15);
        if (arow >= NN) arow = NN - 1;           // clamp reads; writes guarded

        bf16x8 af[8];
#pragma unroll
        for (int kc = 0; kc < 4; ++kc)
            af[kc] = *(const bf16x8*)(meanb + (size_t)arow * 128 + kc * 32 + kg);
#pragma unroll
        for (int kc = 4; kc < 8; ++kc) {
            if (L1) {
                const float* ap = xf + (size_t)arow * 128 + (kc - 4) * 32 + kg;
                float4 a = *(const float4*)ap;
                float4 b = *(const float4*)(ap + 4);
                bf16x8 v;
                v[0] = (short)f2b(a.x); v[1] = (short)f2b(a.y);
                v[2] = (short)f2b(a.z); v[3] = (short)f2b(a.w);
                v[4] = (short)f2b(b.x); v[5] = (short)f2b(b.y);
                v[6] = (short)f2b(b.z); v[7] = (short)f2b(b.w);
                af[kc] = v;
            } else {
                af[kc] = *(const bf16x8*)(ah + (size_t)arow * 128 + (kc - 4) * 32 + kg);
            }
        }

        f32x4 acc[4] = {};
#pragma unroll
        for (int kc = 0; kc < 8; ++kc) {
#pragma unroll
            for (int t = 0; t < 4; ++t) {
                bf16x8 bf = *(const bf16x8*)&WbL[kc][c0 + t * 16 + c][kg];
                acc[t] = __builtin_amdgcn_mfma_f32_16x16x32_bf16(af[kc], bf, acc[t], 0, 0, 0);
            }
        }

        int rbase = r0 + (lane >> 4) * 4;
#pragma unroll
        for (int t = 0; t < 4; ++t) {
#pragma unroll
            for (int i = 0; i < 4; ++i) {
                int r = rbase + i;
                if (r < NN) {
                    float v = acc[t][i] + bj[t];
                    if (L1) {
                        v = fmaxf(v, 0.f);
                        outh[(size_t)r * 128 + c0 + t * 16 + c] = f2b(v);
                        int q = __builtin_amdgcn_cvt_pk_fp8_f32(v, v, 0, false);
                        outq[(size_t)r * 128 + c0 + t * 16 + c] = (unsigned char)q;
                    } else {
                        outf[(size_t)r * 128 + c0 + t * 16 + c] = v;
                    }
                }
            }
        }
    }
}

// ---------------- launch ----------------

extern "C" void kernel_launch(void* const* d_in, const int* in_sizes, int n_in,
                              void* d_out, int out_size, void* d_ws, size_t ws_size,
                              hipStream_t stream) {
    const float* x   = (const float*)d_in[0];
    const int*   ei  = (const int*)d_in[1];
    const float* W1l = (const float*)d_in[2];
    const float* b1  = (const float*)d_in[3];
    const float* W1r = (const float*)d_in[4];
    const float* W2l = (const float*)d_in[5];
    const float* b2  = (const float*)d_in[6];
    const float* W2r = (const float*)d_in[7];
    float* out = (float*)d_out;

    const int* src = ei;
    const int* dst = ei + NE;

    char* ws = (char*)d_ws;
    size_t off = 0;
    auto carve = [&](size_t bytes) {
        char* p = ws + off;
        off = (off + bytes + 255) & ~(size_t)255;
        return p;
    };
    int*            rp     = (int*)carve((NN + 1) * sizeof(int));
    int*            g_fill = (int*)carve(512 * sizeof(int));
    unsigned short* su     = (unsigned short*)carve((size_t)NE * sizeof(unsigned short));
    unsigned*       xq     = (unsigned*)carve((size_t)NN * DD);                 // fp8 x
    unsigned char*  hq     = (unsigned char*)carve((size_t)NN * DD);            // fp8 relu(h)
    ushort*         meanb  = (ushort*)carve((size_t)NN * DD * sizeof(ushort));  // bf16 mean
    ushort*         hh     = (ushort*)carve((size_t)NN * DD * sizeof(ushort));  // bf16 relu(h)
    ushort*         Wsw1   = (ushort*)carve(128 * 256 * sizeof(ushort));
    ushort*         Wsw2   = (ushort*)carve(128 * 256 * sizeof(ushort));
    unsigned*       l1out  = (unsigned*)hh;   // 8.0MB <= 12.8MB; dead before gemm1 writes hh

    hipMemsetAsync(g_fill, 0, 512 * sizeof(int), stream);

    l1_scatter<<<NB1, L1T, 0, stream>>>(src, dst, g_fill, l1out,
                                        x, xq, W1l, W1r, W2l, W2r, Wsw1, Wsw2);
    l2_kernel<<<NBUCK, 1024, 0, stream>>>(g_fill, l1out, su, rp);

    // layer 1
    agg_fp8<<<AGRID, 256, 0, stream>>>((const unsigned char*)xq, rp, su, meanb);
    gemm_mfma<1><<<GGRID, 256, 0, stream>>>(meanb, x, nullptr, Wsw1, b1, nullptr, hh, hq);

    // layer 2
    agg_fp8<<<AGRID, 256, 0, stream>>>(hq, rp, su, meanb);
    gemm_mfma<0><<<GGRID, 256, 0, stream>>>(meanb, nullptr, hh, Wsw2, b2, out, nullptr, nullptr);
}